// Round 5
// baseline (129.536 us; speedup 1.0000x reference)
//
#include <hip/hip_runtime.h>

typedef float v2f __attribute__((ext_vector_type(2)));

static constexpr int N_AGENTS = 64;   // = wave size; one lane per agent/edge
static constexpr int H_DIM    = 8;
static constexpr int ROWS     = 4;    // rows per wave-iteration (2x v2f packed)

__device__ __forceinline__ float fast_rcp(float v) {
#if __has_builtin(__builtin_amdgcn_rcpf)
    return __builtin_amdgcn_rcpf(v);    // v_rcp_f32
#else
    return 1.0f / v;
#endif
}

__device__ __forceinline__ float clamp1(float v) {
#if __has_builtin(__builtin_amdgcn_fmed3f)
    return __builtin_amdgcn_fmed3f(v, -1.0f, 1.0f);  // v_med3_f32, inline consts
#else
    return fminf(fmaxf(v, -1.0f), 1.0f);
#endif
}

__device__ __forceinline__ v2f fma2(v2f a, v2f b, v2f c) {
    return __builtin_elementwise_fma(a, b, c);   // -> v_pk_fma_f32
}
__device__ __forceinline__ v2f splat(float s) { return (v2f){s, s}; }

// Padé[7/6] tanh (continued-fraction truncation):
//   tanh(t) ~= t*(u^3+378u^2+17325u+135135)/(28u^3+3150u^2+62370u+135135), u=t^2
// Monotone, crosses 1.0 at t~=5, <=1.042 for |t|<=14 -> clamping OUTPUT to
// [-1,1] (v_med3, inline consts) gives uniform abs err <= ~1e-4 with NO input
// clamp and no overflow. The 4 divisions per group are batched into ONE
// v_rcp_f32 (per packed component) + muls: trans ops drop 32/row -> 4/row.
__device__ __forceinline__ void tanh4_acc(const v2f t[4], const float w[4], v2f& acc) {
    v2f n[4], d[4];
#pragma unroll
    for (int j = 0; j < 4; ++j) {
        const v2f u = t[j] * t[j];
        v2f s = u + splat(378.0f);
        s = fma2(s, u, splat(17325.0f));
        n[j] = fma2(s, u, splat(135135.0f));
        v2f q = fma2(u, splat(28.0f), splat(3150.0f));
        q = fma2(q, u, splat(62370.0f));
        d[j] = fma2(q, u, splat(135135.0f));
    }
    // batched reciprocal of the 4 denominators (per packed component)
    const v2f p01 = d[0] * d[1];
    const v2f p23 = d[2] * d[3];
    const v2f P   = p01 * p23;
    v2f r; r.x = fast_rcp(P.x); r.y = fast_rcp(P.y);
    const v2f q23 = r * p23, q01 = r * p01;
    v2f inv[4];
    inv[0] = q23 * d[1];
    inv[1] = q23 * d[0];
    inv[2] = q01 * d[3];
    inv[3] = q01 * d[2];
#pragma unroll
    for (int j = 0; j < 4; ++j) {
        v2f m = t[j] * n[j];
        m = m * inv[j];
        m.x = clamp1(m.x);
        m.y = clamp1(m.y);
        acc = fma2(m, splat(w[j]), acc);
    }
}

__global__ __launch_bounds__(256) void networked_ode_kernel(
    const float* __restrict__ x,    // [B, N] f32
    const float* __restrict__ W1,   // [N, H]
    const float* __restrict__ b1,   // [N, H]
    const float* __restrict__ W2,   // [N, H]
    const float* __restrict__ b2,   // [N]
    const float* __restrict__ Wc1,  // [2, H]
    const float* __restrict__ bc1,  // [H]
    const float* __restrict__ Wc2,  // [H]
    const float* __restrict__ bc2,  // [1]
    const int* __restrict__ send_idx,  // [N]
    const int* __restrict__ recv_idx,  // [N]
    float* __restrict__ out,        // [B, N] f32
    int B)
{
    const int lane           = threadIdx.x & 63;
    const int wave_in_block  = threadIdx.x >> 6;
    const int waves_per_blk  = blockDim.x >> 6;
    const int gwave          = blockIdx.x * waves_per_blk + wave_in_block;
    const int total_waves    = gridDim.x * waves_per_blk;

    // ---- per-lane (agent) intrinsic weights (raw; Pade works on raw a)
    float w1v[H_DIM], b1v[H_DIM], w2v[H_DIM];
#pragma unroll
    for (int h = 0; h < H_DIM; ++h) {
        w1v[h] = W1[lane * H_DIM + h];
        b1v[h] = b1[lane * H_DIM + h];
        w2v[h] = W2[lane * H_DIM + h];
    }
    const float b2v = b2[lane];

    // ---- wave-uniform coupling weights (compiler -> SGPRs)
    float wcs[H_DIM], wcr[H_DIM], bc1v[H_DIM], wc2v[H_DIM];
#pragma unroll
    for (int h = 0; h < H_DIM; ++h) {
        wcs[h]  = Wc1[h];          // Wc1[0][h] (x_send)
        wcr[h]  = Wc1[H_DIM + h];  // Wc1[1][h] (x_recv)
        bc1v[h] = bc1[h];
        wc2v[h] = Wc2[h];
    }
    const float bc2v = bc2[0];

    // ---- edge endpoints for edge e = lane
    const int sidx = send_idx[lane];
    const int ridx = recv_idx[lane];

    // ring topology: send is the identity permutation in practice; detect
    // wave-uniformly to skip 2 of 4 shuffles per row (generic fallback kept).
    const bool send_is_id = (__ballot(sidx == lane) == ~0ull);

    // ---- scatter-add becomes gather via inverse permutation (computed once)
    __shared__ int inv_r_s[256], inv_s_s[256];
    const int base = wave_in_block * 64;
    inv_r_s[base + ridx] = lane;
    inv_s_s[base + sidx] = lane;
    __syncthreads();
    const int inv_r = inv_r_s[base + lane];  // edge whose recv == my agent
    const int inv_s = inv_s_s[base + lane];  // edge whose send == my agent

    // ---- grid-stride, 4 rows per iteration (2x v2f) for ILP + packed math
    for (int row0 = gwave * ROWS; row0 < B; row0 += total_waves * ROWS) {
        float xv[ROWS], xs[ROWS], xr[ROWS];
#pragma unroll
        for (int k = 0; k < ROWS; ++k) {
            const int row = row0 + k;
            xv[k] = (row < B) ? x[(size_t)row * N_AGENTS + lane] : 0.0f;
        }
#pragma unroll
        for (int k = 0; k < ROWS; ++k) xr[k] = __shfl(xv[k], ridx, 64);
        if (send_is_id) {
#pragma unroll
            for (int k = 0; k < ROWS; ++k) xs[k] = xv[k];
        } else {
#pragma unroll
            for (int k = 0; k < ROWS; ++k) xs[k] = __shfl(xv[k], sidx, 64);
        }

        v2f XV[2] = {{xv[0], xv[1]}, {xv[2], xv[3]}};
        v2f XS[2] = {{xs[0], xs[1]}, {xs[2], xs[3]}};
        v2f XR[2] = {{xr[0], xr[1]}, {xr[2], xr[3]}};
        v2f C[2]  = {splat(bc2v), splat(bc2v)};
        v2f A[2]  = {splat(b2v), splat(b2v)};

#pragma unroll
        for (int p = 0; p < 2; ++p) {
            // coupling MLP (edge = lane): 2 groups of 4 hidden units
#pragma unroll
            for (int g = 0; g < 2; ++g) {
                v2f t[4];
#pragma unroll
                for (int j = 0; j < 4; ++j) {
                    const int h = g * 4 + j;
                    t[j] = fma2(XS[p], splat(wcs[h]),
                           fma2(XR[p], splat(wcr[h]), splat(bc1v[h])));
                }
                tanh4_acc(t, &wc2v[g * 4], C[p]);
            }
            // intrinsic MLP (agent = lane): 2 groups of 4 hidden units
#pragma unroll
            for (int g = 0; g < 2; ++g) {
                v2f t[4];
#pragma unroll
                for (int j = 0; j < 4; ++j) {
                    const int h = g * 4 + j;
                    t[j] = fma2(XV[p], splat(w1v[h]), splat(b1v[h]));
                }
                tanh4_acc(t, &w2v[g * 4], A[p]);
            }
        }

        // symmetric scatter: +contrib at receiver, -contrib at sender
        const float cv[ROWS] = {C[0].x, C[0].y, C[1].x, C[1].y};
        const float av[ROWS] = {A[0].x, A[0].y, A[1].x, A[1].y};
#pragma unroll
        for (int k = 0; k < ROWS; ++k) {
            const float cr = __shfl(cv[k], inv_r, 64);
            const float cs = send_is_id ? cv[k] : __shfl(cv[k], inv_s, 64);
            const int row = row0 + k;
            if (row < B)
                out[(size_t)row * N_AGENTS + lane] = av[k] + cr - cs;
        }
    }
}

extern "C" void kernel_launch(void* const* d_in, const int* in_sizes, int n_in,
                              void* d_out, int out_size, void* d_ws, size_t ws_size,
                              hipStream_t stream) {
    const float* x   = (const float*)d_in[0];
    const float* W1  = (const float*)d_in[1];
    const float* b1  = (const float*)d_in[2];
    const float* W2  = (const float*)d_in[3];
    const float* b2  = (const float*)d_in[4];
    const float* Wc1 = (const float*)d_in[5];
    const float* bc1 = (const float*)d_in[6];
    const float* Wc2 = (const float*)d_in[7];
    const float* bc2 = (const float*)d_in[8];
    const int* send_idx = (const int*)d_in[9];
    const int* recv_idx = (const int*)d_in[10];

    const int B = in_sizes[0] / N_AGENTS;   // 131072

    // 2048 blocks x 4 waves = 8192 waves (8/SIMD); ROWS=4 -> 4 iters/wave
    const int blocks = 2048;
    networked_ode_kernel<<<blocks, dim3(256), 0, stream>>>(
        x, W1, b1, W2, b2, Wc1, bc1, Wc2, bc2, send_idx, recv_idx,
        (float*)d_out, B);
}